// Round 2
// baseline (1083.913 us; speedup 1.0000x reference)
//
#include <hip/hip_runtime.h>
#include <hip/hip_bf16.h>

#define TDIM 1024
#define NEXP 8
#define NHID 4096

typedef __hip_bfloat16 bf16;
typedef __attribute__((ext_vector_type(8))) short bf16x8;
typedef __attribute__((ext_vector_type(8))) unsigned short u16x8;
typedef __attribute__((ext_vector_type(4))) float f32x4;

__device__ __forceinline__ void gload_lds16(void* lds, const void* g) {
  __builtin_amdgcn_global_load_lds(
      (const __attribute__((address_space(1))) unsigned int*)g,
      (__attribute__((address_space(3))) unsigned int*)lds, 16, 0, 0);
}

__device__ __forceinline__ unsigned short f2bf_bits(float f) {
  __hip_bfloat16 b = __float2bfloat16(f);
  unsigned short u;
  __builtin_memcpy(&u, &b, 2);
  return u;
}

__device__ __forceinline__ float bf2f(unsigned short u) {
  union { unsigned int i; float f; } c;
  c.i = ((unsigned int)u) << 16;
  return c.f;
}

// ---------------- x -> bf16 ----------------
__global__ void cvt_x_kernel(const float* __restrict__ x, bf16* __restrict__ xb, int n4) {
  int i = blockIdx.x * blockDim.x + threadIdx.x;
  if (i >= n4) return;
  float4 v = reinterpret_cast<const float4*>(x)[i];
  ushort4 o;
  o.x = f2bf_bits(v.x);
  o.y = f2bf_bits(v.y);
  o.z = f2bf_bits(v.z);
  o.w = f2bf_bits(v.w);
  reinterpret_cast<ushort4*>(xb)[i] = o;
}

// ---------------- transpose + convert: in [E][R][C] f32 -> out [E][C][R] bf16 ----------------
// 64x64 tiles, float4 loads, 16B bf16 stores.
__global__ __launch_bounds__(256) void transpose_cvt_kernel(const float* __restrict__ in,
                                                            bf16* __restrict__ out, int R, int C) {
  __shared__ float tile[64][65];
  const size_t eoff = (size_t)blockIdx.z * R * C;
  const float* src = in + eoff;
  bf16* dst = out + eoff;
  const int c0 = blockIdx.x * 64, r0 = blockIdx.y * 64;
  const int tid = threadIdx.x;
#pragma unroll
  for (int i = 0; i < 4; ++i) {
    int s = tid + i * 256;
    int r = s >> 4, cg = (s & 15) * 4;
    float4 v = *reinterpret_cast<const float4*>(src + (size_t)(r0 + r) * C + c0 + cg);
    tile[r][cg] = v.x;
    tile[r][cg + 1] = v.y;
    tile[r][cg + 2] = v.z;
    tile[r][cg + 3] = v.w;
  }
  __syncthreads();
#pragma unroll
  for (int i = 0; i < 2; ++i) {
    int s = tid + i * 256;
    int c = s >> 3, rg = (s & 7) * 8;
    u16x8 o;
#pragma unroll
    for (int j = 0; j < 8; ++j) o[j] = f2bf_bits(tile[rg + j][c]);
    *reinterpret_cast<u16x8*>(dst + (size_t)(c0 + c) * R + r0 + rg) = o;
  }
}

// ---------------- router: fp32 logits, top-2, softmax ----------------
__global__ void router_kernel(const float* __restrict__ x, const float* __restrict__ Wr,
                              int* __restrict__ idx, float* __restrict__ wtok,
                              int* __restrict__ cnt, int T) {
  int wave = (blockIdx.x * blockDim.x + threadIdx.x) >> 6;
  int lane = threadIdx.x & 63;
  if (wave >= T) return;
  const float4* xr4 = reinterpret_cast<const float4*>(x + (size_t)wave * TDIM);
  const float4* wr4 = reinterpret_cast<const float4*>(Wr);
  float acc[NEXP];
#pragma unroll
  for (int e = 0; e < NEXP; ++e) acc[e] = 0.f;
#pragma unroll
  for (int i = 0; i < TDIM / 256; ++i) {
    float4 xv = xr4[lane + i * 64];
    int row = (lane + i * 64) * 4;
#pragma unroll
    for (int j = 0; j < 4; ++j) {
      float xs = (&xv.x)[j];
      float4 wa = wr4[(row + j) * 2];
      float4 wb = wr4[(row + j) * 2 + 1];
      acc[0] += xs * wa.x;
      acc[1] += xs * wa.y;
      acc[2] += xs * wa.z;
      acc[3] += xs * wa.w;
      acc[4] += xs * wb.x;
      acc[5] += xs * wb.y;
      acc[6] += xs * wb.z;
      acc[7] += xs * wb.w;
    }
  }
#pragma unroll
  for (int e = 0; e < NEXP; ++e) {
    float v = acc[e];
#pragma unroll
    for (int s = 32; s; s >>= 1) v += __shfl_xor(v, s);
    acc[e] = v;
  }
  if (lane == 0) {
    int e0 = 0;
    float l0 = acc[0];
    for (int e = 1; e < NEXP; ++e)
      if (acc[e] > l0) { l0 = acc[e]; e0 = e; }
    int e1 = -1;
    float l1 = -INFINITY;
    for (int e = 0; e < NEXP; ++e)
      if (e != e0 && acc[e] > l1) { l1 = acc[e]; e1 = e; }
    float z = __expf(l1 - l0);
    float w0 = 1.f / (1.f + z);
    float w1 = z / (1.f + z);
    idx[wave * 2] = e0;
    idx[wave * 2 + 1] = e1;
    wtok[wave * 2] = w0;
    wtok[wave * 2 + 1] = w1;
    atomicAdd(&cnt[e0], 1);
    atomicAdd(&cnt[e1], 1);
  }
}

__global__ void scan_kernel(const int* __restrict__ cnt, int* __restrict__ offs) {
  if (threadIdx.x == 0 && blockIdx.x == 0) {
    int s = 0;
    for (int e = 0; e < NEXP; ++e) { offs[e] = s; s += cnt[e]; }
  }
}

__global__ void build_perm_kernel(const int* __restrict__ idx, const int* __restrict__ offs,
                                  int* __restrict__ fill, int* __restrict__ perm,
                                  int* __restrict__ islot, int T) {
  int t = blockIdx.x * blockDim.x + threadIdx.x;
  if (t >= T) return;
#pragma unroll
  for (int k = 0; k < 2; ++k) {
    int e = idx[t * 2 + k];
    int p = offs[e] + atomicAdd(&fill[e], 1);
    perm[p] = t;
    islot[t * 2 + k] = p;
  }
}

// ---------------- grouped GEMM, 256x256x64 double-buffered 2-phase ----------------
// 512 threads = 8 waves (2m x 4n), per-wave output 128x64.
// A rows gathered via perm (GEMM1) or contiguous grouped rows (GEMM2).
// BT is [E][N][K] bf16 (pre-transposed, K-contiguous).
template <int KD, int ND, bool GATHER, bool GELU>
__global__ __launch_bounds__(512, 2) void moe_gemm(
    const bf16* __restrict__ A, const bf16* __restrict__ BT, const float* __restrict__ bias,
    const int* __restrict__ perm, const int* __restrict__ cnt, const int* __restrict__ offs,
    bf16* __restrict__ Dst, int nm, int nn) {
  __shared__ short sA[2][256 * 64];
  __shared__ short sB[2][256 * 64];

  // bijective XCD-chunked swizzle (nwg % 8 == 0 by construction)
  const int nwg = NEXP * nm * nn;
  const int bid = blockIdx.x;
  const int wg = (bid & 7) * (nwg >> 3) + (bid >> 3);
  const int e = wg / (nm * nn);
  const int rem = wg % (nm * nn);
  const int mb = rem / nn, nb = rem % nn;

  const int ce = cnt[e];
  const int m0 = mb * 256;
  if (m0 >= ce) return;
  const int base = offs[e];
  const int n0 = nb * 256;
  const int tid = threadIdx.x;
  const int lane = tid & 63;
  const int wid = tid >> 6;
  const int wm = wid >> 2, wn = wid & 3;

  // staging: thread handles 16B slots tid + i*512 of each 2048-slot buffer.
  // slot s -> row s>>3 (0..255), k-elems (s&7)*8.  LDS dest = wave-uniform base + lane*16. ok.
  const int trow = tid >> 3;       // 0..63
  const int tk = (tid & 7) * 8;    // k elem offset (fixed per thread)
  const bf16* aSrc[4];
  const bf16* bSrc[4];
#pragma unroll
  for (int i = 0; i < 4; ++i) {
    int g = m0 + trow + i * 64;
    if (g > ce - 1) g = ce - 1;
    size_t arow = GATHER ? (size_t)perm[base + g] : (size_t)(base + g);
    aSrc[i] = A + arow * KD + tk;
    bSrc[i] = BT + ((size_t)e * ND + n0 + trow + i * 64) * KD + tk;
  }

  f32x4 acc[8][4];
#pragma unroll
  for (int m = 0; m < 8; ++m)
#pragma unroll
    for (int n = 0; n < 4; ++n) acc[m][n] = (f32x4){0.f, 0.f, 0.f, 0.f};

  const int lcol = lane & 15;
  const int lkg = (lane >> 4) * 8;

  // prologue
#pragma unroll
  for (int i = 0; i < 4; ++i) {
    gload_lds16((char*)sA[0] + tid * 16 + i * 8192, aSrc[i]);
    gload_lds16((char*)sB[0] + tid * 16 + i * 8192, bSrc[i]);
  }
  __syncthreads();

  const int NT = KD / 64;
  for (int kt = 0; kt < NT; ++kt) {
    const int cur = kt & 1;
    if (kt + 1 < NT) {
      const int k0 = (kt + 1) * 64;
#pragma unroll
      for (int i = 0; i < 4; ++i) {
        gload_lds16((char*)sA[cur ^ 1] + tid * 16 + i * 8192, aSrc[i] + k0);
        gload_lds16((char*)sB[cur ^ 1] + tid * 16 + i * 8192, bSrc[i] + k0);
      }
    }
    const short* sAb = sA[cur];
    const short* sBb = sB[cur];
    bf16x8 bfr[8];
#pragma unroll
    for (int n = 0; n < 4; ++n)
#pragma unroll
      for (int kk = 0; kk < 2; ++kk)
        bfr[n * 2 + kk] =
            *(const bf16x8*)(sBb + ((wn * 64 + n * 16 + lcol) * 64 + kk * 32 + lkg));
#pragma unroll
    for (int m = 0; m < 8; ++m) {
      const short* ap = sAb + ((wm * 128 + m * 16 + lcol) * 64 + lkg);
      bf16x8 a0 = *(const bf16x8*)(ap);
      bf16x8 a1 = *(const bf16x8*)(ap + 32);
#pragma unroll
      for (int n = 0; n < 4; ++n) {
        acc[m][n] = __builtin_amdgcn_mfma_f32_16x16x32_bf16(a0, bfr[n * 2], acc[m][n], 0, 0, 0);
        acc[m][n] = __builtin_amdgcn_mfma_f32_16x16x32_bf16(a1, bfr[n * 2 + 1], acc[m][n], 0, 0, 0);
      }
    }
    __syncthreads();  // drains vmcnt(0) too: next-tile loads resident, all reads of cur done
  }

  // epilogue. C mapping: row = wm*128 + m*16 + (lane>>4)*4 + r ; col = wn*64 + n*16 + (lane&15)
  float bv[4];
#pragma unroll
  for (int n = 0; n < 4; ++n) bv[n] = bias[e * ND + n0 + wn * 64 + n * 16 + lcol];
  const int lr4 = (lane >> 4) * 4;
#pragma unroll
  for (int m = 0; m < 8; ++m)
#pragma unroll
    for (int r = 0; r < 4; ++r) {
      int grow = m0 + wm * 128 + m * 16 + lr4 + r;
      if (grow < ce) {
        bf16* drow = Dst + (size_t)(base + grow) * ND;
#pragma unroll
        for (int n = 0; n < 4; ++n) {
          int col = n0 + wn * 64 + n * 16 + lcol;
          float v = acc[m][n][r] + bv[n];
          if (GELU) v = 0.5f * v * (1.0f + erff(v * 0.70710678118654752f));
          drow[col] = __float2bfloat16(v);
        }
      }
    }
}

// ---------------- combine: out[t] = w0*y[slot0] + w1*y[slot1] ----------------
__global__ void combine_kernel(const bf16* __restrict__ y, const int* __restrict__ islot,
                               const float* __restrict__ wtok, float* __restrict__ out) {
  const int t = blockIdx.x;
  const int d = threadIdx.x * 4;
  const int s0 = islot[t * 2], s1 = islot[t * 2 + 1];
  const float w0 = wtok[t * 2], w1 = wtok[t * 2 + 1];
  ushort4 ya = *reinterpret_cast<const ushort4*>(y + (size_t)s0 * TDIM + d);
  ushort4 yb = *reinterpret_cast<const ushort4*>(y + (size_t)s1 * TDIM + d);
  float4 o;
  o.x = w0 * bf2f(ya.x) + w1 * bf2f(yb.x);
  o.y = w0 * bf2f(ya.y) + w1 * bf2f(yb.y);
  o.z = w0 * bf2f(ya.z) + w1 * bf2f(yb.z);
  o.w = w0 * bf2f(ya.w) + w1 * bf2f(yb.w);
  *reinterpret_cast<float4*>(out + (size_t)t * TDIM + d) = o;
}

extern "C" void kernel_launch(void* const* d_in, const int* in_sizes, int n_in, void* d_out,
                              int out_size, void* d_ws, size_t ws_size, hipStream_t stream) {
  const float* x = (const float*)d_in[0];
  const float* Wr = (const float*)d_in[1];
  const float* W1 = (const float*)d_in[2];
  const float* b1 = (const float*)d_in[3];
  const float* W2 = (const float*)d_in[4];
  const float* b2 = (const float*)d_in[5];
  float* out = (float*)d_out;
  const int T = in_sizes[0] / TDIM;  // 8192

  size_t off = 0;
  auto alloc = [&](size_t bytes) {
    void* q = (char*)d_ws + off;
    off += (bytes + 255) & ~(size_t)255;
    return q;
  };
  bf16* xb = (bf16*)alloc((size_t)T * TDIM * 2);
  bf16* W1T = (bf16*)alloc((size_t)NEXP * TDIM * NHID * 2);
  bf16* W2T = (bf16*)alloc((size_t)NEXP * TDIM * NHID * 2);
  bf16* h = (bf16*)alloc((size_t)2 * T * NHID * 2);
  int* idx = (int*)alloc((size_t)T * 2 * 4);
  float* wtok = (float*)alloc((size_t)T * 2 * 4);
  int* perm = (int*)alloc((size_t)T * 2 * 4);
  int* islot = (int*)alloc((size_t)T * 2 * 4);
  int* cnt = (int*)alloc(256);  // cnt[8] | fill[8] | offs[8]
  int* fill = cnt + 8;
  int* offs = cnt + 16;
  // y (32 MB bf16) aliases W1T (64 MB): W1T is dead after GEMM1, y written by GEMM2 (later
  // on the same stream), read by combine. Saves workspace.
  bf16* y = W1T;

  hipMemsetAsync(cnt, 0, 64, stream);  // cnt + fill

  cvt_x_kernel<<<(T * TDIM / 4 + 255) / 256, 256, 0, stream>>>(x, xb, T * TDIM / 4);
  transpose_cvt_kernel<<<dim3(NHID / 64, TDIM / 64, NEXP), 256, 0, stream>>>(W1, W1T, TDIM, NHID);
  transpose_cvt_kernel<<<dim3(TDIM / 64, NHID / 64, NEXP), 256, 0, stream>>>(W2, W2T, NHID, TDIM);
  router_kernel<<<T / 4, 256, 0, stream>>>(x, Wr, idx, wtok, cnt, T);
  scan_kernel<<<1, 64, 0, stream>>>(cnt, offs);
  build_perm_kernel<<<(T + 255) / 256, 256, 0, stream>>>(idx, offs, fill, perm, islot, T);

  // GEMM1: h[slot] = gelu(x[perm[slot]] @ W1[e] + b1[e]); grid nm=32 (worst-case 8192 rows), nn=16
  moe_gemm<TDIM, NHID, true, true><<<NEXP * 32 * 16, 512, 0, stream>>>(
      xb, W1T, b1, perm, cnt, offs, h, 32, 16);
  // GEMM2: y[slot] = h[slot] @ W2[e] + b2[e]; nm=32, nn=4
  moe_gemm<NHID, TDIM, false, false><<<NEXP * 32 * 4, 512, 0, stream>>>(
      h, W2T, b2, perm, cnt, offs, y, 32, 4);

  combine_kernel<<<T, 256, 0, stream>>>(y, islot, wtok, out);
}

// Round 3
// 826.723 us; speedup vs baseline: 1.3111x; 1.3111x over previous
//
#include <hip/hip_runtime.h>
#include <hip/hip_bf16.h>

#define TDIM 1024
#define NEXP 8
#define NHID 4096

typedef __hip_bfloat16 bf16;
typedef __attribute__((ext_vector_type(8))) short bf16x8;
typedef __attribute__((ext_vector_type(8))) unsigned short u16x8;
typedef __attribute__((ext_vector_type(4))) float f32x4;

__device__ __forceinline__ void gload_lds16(void* lds, const void* g) {
  __builtin_amdgcn_global_load_lds(
      (const __attribute__((address_space(1))) unsigned int*)g,
      (__attribute__((address_space(3))) unsigned int*)lds, 16, 0, 0);
}

__device__ __forceinline__ unsigned short f2bf_bits(float f) {
  __hip_bfloat16 b = __float2bfloat16(f);
  unsigned short u;
  __builtin_memcpy(&u, &b, 2);
  return u;
}

__device__ __forceinline__ float bf2f(unsigned short u) {
  union { unsigned int i; float f; } c;
  c.i = ((unsigned int)u) << 16;
  return c.f;
}

// ---------------- x -> bf16 ----------------
__global__ void cvt_x_kernel(const float* __restrict__ x, bf16* __restrict__ xb, int n4) {
  int i = blockIdx.x * blockDim.x + threadIdx.x;
  if (i >= n4) return;
  float4 v = reinterpret_cast<const float4*>(x)[i];
  ushort4 o;
  o.x = f2bf_bits(v.x);
  o.y = f2bf_bits(v.y);
  o.z = f2bf_bits(v.z);
  o.w = f2bf_bits(v.w);
  reinterpret_cast<ushort4*>(xb)[i] = o;
}

// ---------------- transpose + convert: in [E][R][C] f32 -> out [E][C][R] bf16 ----------------
__global__ __launch_bounds__(256) void transpose_cvt_kernel(const float* __restrict__ in,
                                                            bf16* __restrict__ out, int R, int C) {
  __shared__ float tile[64][65];
  const size_t eoff = (size_t)blockIdx.z * R * C;
  const float* src = in + eoff;
  bf16* dst = out + eoff;
  const int c0 = blockIdx.x * 64, r0 = blockIdx.y * 64;
  const int tid = threadIdx.x;
#pragma unroll
  for (int i = 0; i < 4; ++i) {
    int s = tid + i * 256;
    int r = s >> 4, cg = (s & 15) * 4;
    float4 v = *reinterpret_cast<const float4*>(src + (size_t)(r0 + r) * C + c0 + cg);
    tile[r][cg] = v.x;
    tile[r][cg + 1] = v.y;
    tile[r][cg + 2] = v.z;
    tile[r][cg + 3] = v.w;
  }
  __syncthreads();
#pragma unroll
  for (int i = 0; i < 2; ++i) {
    int s = tid + i * 256;
    int c = s >> 3, rg = (s & 7) * 8;
    u16x8 o;
#pragma unroll
    for (int j = 0; j < 8; ++j) o[j] = f2bf_bits(tile[rg + j][c]);
    *reinterpret_cast<u16x8*>(dst + (size_t)(c0 + c) * R + r0 + rg) = o;
  }
}

// ---------------- router: fp32 logits, top-2, softmax ----------------
__global__ void router_kernel(const float* __restrict__ x, const float* __restrict__ Wr,
                              int* __restrict__ idx, float* __restrict__ wtok,
                              int* __restrict__ cnt, int T) {
  int wave = (blockIdx.x * blockDim.x + threadIdx.x) >> 6;
  int lane = threadIdx.x & 63;
  if (wave >= T) return;
  const float4* xr4 = reinterpret_cast<const float4*>(x + (size_t)wave * TDIM);
  const float4* wr4 = reinterpret_cast<const float4*>(Wr);
  float acc[NEXP];
#pragma unroll
  for (int e = 0; e < NEXP; ++e) acc[e] = 0.f;
#pragma unroll
  for (int i = 0; i < TDIM / 256; ++i) {
    float4 xv = xr4[lane + i * 64];
    int row = (lane + i * 64) * 4;
#pragma unroll
    for (int j = 0; j < 4; ++j) {
      float xs = (&xv.x)[j];
      float4 wa = wr4[(row + j) * 2];
      float4 wb = wr4[(row + j) * 2 + 1];
      acc[0] += xs * wa.x;
      acc[1] += xs * wa.y;
      acc[2] += xs * wa.z;
      acc[3] += xs * wa.w;
      acc[4] += xs * wb.x;
      acc[5] += xs * wb.y;
      acc[6] += xs * wb.z;
      acc[7] += xs * wb.w;
    }
  }
#pragma unroll
  for (int e = 0; e < NEXP; ++e) {
    float v = acc[e];
#pragma unroll
    for (int s = 32; s; s >>= 1) v += __shfl_xor(v, s);
    acc[e] = v;
  }
  if (lane == 0) {
    int e0 = 0;
    float l0 = acc[0];
    for (int e = 1; e < NEXP; ++e)
      if (acc[e] > l0) { l0 = acc[e]; e0 = e; }
    int e1 = -1;
    float l1 = -INFINITY;
    for (int e = 0; e < NEXP; ++e)
      if (e != e0 && acc[e] > l1) { l1 = acc[e]; e1 = e; }
    float z = __expf(l1 - l0);
    float w0 = 1.f / (1.f + z);
    float w1 = z / (1.f + z);
    idx[wave * 2] = e0;
    idx[wave * 2 + 1] = e1;
    wtok[wave * 2] = w0;
    wtok[wave * 2 + 1] = w1;
    atomicAdd(&cnt[e0], 1);
    atomicAdd(&cnt[e1], 1);
  }
}

__global__ void scan_kernel(const int* __restrict__ cnt, int* __restrict__ offs) {
  if (threadIdx.x == 0 && blockIdx.x == 0) {
    int s = 0;
    for (int e = 0; e < NEXP; ++e) { offs[e] = s; s += cnt[e]; }
  }
}

__global__ void build_perm_kernel(const int* __restrict__ idx, const int* __restrict__ offs,
                                  int* __restrict__ fill, int* __restrict__ perm,
                                  int* __restrict__ islot, int T) {
  int t = blockIdx.x * blockDim.x + threadIdx.x;
  if (t >= T) return;
#pragma unroll
  for (int k = 0; k < 2; ++k) {
    int e = idx[t * 2 + k];
    int p = offs[e] + atomicAdd(&fill[e], 1);
    perm[p] = t;
    islot[t * 2 + k] = p;
  }
}

// ---------------- grouped GEMM: 256x256x64, 8-phase, counted vmcnt, T2 swizzle ----------------
// 512 threads = 8 waves (2m x 4n). Per-wave output strided: rows qm*128+wm*64+mm*16,
// cols qn*128+wn*32+n2*16, so phase quadrant (qm,qn) touches exactly A-half qm, B-half qn.
// LDS 128 KiB: [buf][op A/B][half] x (128x64 bf16), XOR-swizzled byte^=(row&7)<<4,
// staged by global_load_lds with inverse-swizzled global source (rule #21).
// Phase p: stage(op=p&1, half=(p>>1)&1 of sbuf) -> vmcnt(6) -> s_barrier -> 12 ds_read_b128
// -> lgkmcnt(0) -> setprio(1) 16 MFMA setprio(0).  vmcnt at phases {0,1,2,4,5,6} retires
// exactly the 3/4-phase-old half-tiles; every staged region is >=1 barrier past its last reader.
template <int KD, int ND, bool GATHER, bool GELU>
__global__ __launch_bounds__(512, 2) void moe_gemm8(
    const bf16* __restrict__ A, const bf16* __restrict__ BT, const float* __restrict__ bias,
    const int* __restrict__ perm, const int* __restrict__ cnt, const int* __restrict__ offs,
    bf16* __restrict__ Dst, int nm, int nn) {
  __shared__ short lds[65536];  // 128 KiB: buf*32768 + op*16384 + half*8192 (shorts)

  const int nwg = NEXP * nm * nn;
  const int bid = blockIdx.x;
  const int wg = (bid & 7) * (nwg >> 3) + (bid >> 3);  // bijective: nwg % 8 == 0
  const int e = wg / (nm * nn);
  const int rem = wg % (nm * nn);
  const int mb = rem / nn, nb = rem % nn;

  const int ce = cnt[e];
  const int m0 = mb * 256;
  if (m0 >= ce) return;
  const int base = offs[e];
  const int n0 = nb * 256;
  const int tid = threadIdx.x;
  const int lane = tid & 63;
  const int wid = tid >> 6;
  const int wm = wid >> 2, wn = wid & 3;
  const int lcol = lane & 15;
  const int lkg = (lane >> 4) * 8;

  // per-lane swizzled k offsets (shorts) for fragment reads
  const int kxs0 = ((lkg << 1) ^ ((lcol & 7) << 4)) >> 1;
  const int kxs1 = (((lkg + 32) << 1) ^ ((lcol & 7) << 4)) >> 1;
  int aRow[4], bRow[2];
#pragma unroll
  for (int mm = 0; mm < 4; ++mm) aRow[mm] = (wm * 64 + mm * 16 + lcol) << 6;
#pragma unroll
  for (int n2 = 0; n2 < 2; ++n2) bRow[n2] = (wn * 32 + n2 * 16 + lcol) << 6;

  // staging pointers: slot s = tid + i*512 -> row s>>3 (0..127), kslot s&7;
  // source k pre-swizzled: kslot_src = kslot ^ (row&7)
  const bf16* aP[2][2];
  const bf16* bP[2][2];
#pragma unroll
  for (int h = 0; h < 2; ++h)
#pragma unroll
    for (int i = 0; i < 2; ++i) {
      int s = tid + i * 512;
      int srow = s >> 3;
      int kof = ((s & 7) ^ (srow & 7)) * 8;
      int grow = m0 + h * 128 + srow;
      if (grow > ce - 1) grow = ce - 1;
      size_t arow = GATHER ? (size_t)perm[base + grow] : (size_t)(base + grow);
      aP[h][i] = A + arow * KD + kof;
      bP[h][i] = BT + ((size_t)e * ND + n0 + h * 128 + srow) * KD + kof;
    }

  f32x4 acc[8][4];
#pragma unroll
  for (int m = 0; m < 8; ++m)
#pragma unroll
    for (int n = 0; n < 4; ++n) acc[m][n] = (f32x4){0.f, 0.f, 0.f, 0.f};

#define STAGE(SBUF, OP, HF, kof)                                                     \
  {                                                                                  \
    char* sd = (char*)lds + (SBUF) * 65536 + (OP) * 32768 + (HF) * 16384 + tid * 16; \
    gload_lds16(sd, ((OP) ? bP[HF][0] : aP[HF][0]) + (kof));                         \
    gload_lds16(sd + 8192, ((OP) ? bP[HF][1] : aP[HF][1]) + (kof));                  \
  }

#define PHASE(p, CBUF, SBUF, kof, DO_VM)                                             \
  {                                                                                  \
    constexpr int OP = (p) & 1;      /* == qm; also staged op */                     \
    constexpr int HF = ((p) >> 1) & 1; /* == qn; also staged half */                 \
    STAGE(SBUF, OP, HF, kof);                                                        \
    if (DO_VM) asm volatile("s_waitcnt vmcnt(6)" ::: "memory");                      \
    __builtin_amdgcn_s_barrier();                                                    \
    asm volatile("" ::: "memory");                                                   \
    const short* Ab = lds + (CBUF) * 32768 + OP * 8192;                              \
    const short* Bb = lds + (CBUF) * 32768 + 16384 + HF * 8192;                      \
    bf16x8 fA[4][2], fB[2][2];                                                       \
    _Pragma("unroll") for (int n2 = 0; n2 < 2; ++n2) {                               \
      fB[n2][0] = *(const bf16x8*)(Bb + bRow[n2] + kxs0);                            \
      fB[n2][1] = *(const bf16x8*)(Bb + bRow[n2] + kxs1);                            \
    }                                                                                \
    _Pragma("unroll") for (int mm = 0; mm < 4; ++mm) {                               \
      fA[mm][0] = *(const bf16x8*)(Ab + aRow[mm] + kxs0);                            \
      fA[mm][1] = *(const bf16x8*)(Ab + aRow[mm] + kxs1);                            \
    }                                                                                \
    asm volatile("s_waitcnt lgkmcnt(0)" ::: "memory");                               \
    __builtin_amdgcn_s_setprio(1);                                                   \
    _Pragma("unroll") for (int mm = 0; mm < 4; ++mm)                                 \
        _Pragma("unroll") for (int n2 = 0; n2 < 2; ++n2) {                           \
      acc[OP * 4 + mm][HF * 2 + n2] = __builtin_amdgcn_mfma_f32_16x16x32_bf16(       \
          fA[mm][0], fB[n2][0], acc[OP * 4 + mm][HF * 2 + n2], 0, 0, 0);             \
      acc[OP * 4 + mm][HF * 2 + n2] = __builtin_amdgcn_mfma_f32_16x16x32_bf16(       \
          fA[mm][1], fB[n2][1], acc[OP * 4 + mm][HF * 2 + n2], 0, 0, 0);             \
    }                                                                                \
    __builtin_amdgcn_s_setprio(0);                                                   \
  }

  // prologue: tile 0 -> buf0, in need-order A0,B0,A1,B1
  STAGE(0, 0, 0, 0);
  STAGE(0, 1, 0, 0);
  STAGE(0, 0, 1, 0);
  STAGE(0, 1, 1, 0);

  const int NI = KD / 128;
  for (int itv = 0; itv < NI; ++itv) {
    const int k1 = itv * 128 + 64;           // tile 2it+1 -> buf1 (consumed ph4-7)
    int k2 = itv * 128 + 128;                // tile 2it+2 -> buf0 (consumed next iter)
    if (k2 >= KD) k2 = 0;                    // last iter: wrapped, never consumed
    PHASE(0, 0, 1, k1, 1)
    PHASE(1, 0, 1, k1, 1)
    PHASE(2, 0, 1, k1, 1)
    PHASE(3, 0, 1, k1, 0)
    PHASE(4, 1, 0, k2, 1)
    PHASE(5, 1, 0, k2, 1)
    PHASE(6, 1, 0, k2, 1)
    PHASE(7, 1, 0, k2, 0)
  }
#undef PHASE
#undef STAGE

  // epilogue: row = m0 + qm*128 + wm*64 + mm*16 + (lane>>4)*4 + r ;
  //           col = n0 + qn*128 + wn*32 + n2*16 + lcol
  float bv[4];
#pragma unroll
  for (int ni = 0; ni < 4; ++ni)
    bv[ni] = bias[e * ND + n0 + (ni >> 1) * 128 + wn * 32 + (ni & 1) * 16 + lcol];
  const int lr4 = (lane >> 4) * 4;
#pragma unroll
  for (int mi = 0; mi < 8; ++mi) {
    const int rbase = m0 + (mi >> 2) * 128 + wm * 64 + (mi & 3) * 16 + lr4;
#pragma unroll
    for (int r = 0; r < 4; ++r) {
      int grow = rbase + r;
      if (grow < ce) {
        bf16* drow = Dst + (size_t)(base + grow) * ND;
#pragma unroll
        for (int ni = 0; ni < 4; ++ni) {
          int col = n0 + (ni >> 1) * 128 + wn * 32 + (ni & 1) * 16 + lcol;
          float v = acc[mi][ni][r] + bv[ni];
          if (GELU) v = 0.5f * v * (1.0f + erff(v * 0.70710678118654752f));
          drow[col] = __float2bfloat16(v);
        }
      }
    }
  }
}

// ---------------- combine: out[t] = w0*y[slot0] + w1*y[slot1] ----------------
__global__ void combine_kernel(const bf16* __restrict__ y, const int* __restrict__ islot,
                               const float* __restrict__ wtok, float* __restrict__ out) {
  const int t = blockIdx.x;
  const int d = threadIdx.x * 4;
  const int s0 = islot[t * 2], s1 = islot[t * 2 + 1];
  const float w0 = wtok[t * 2], w1 = wtok[t * 2 + 1];
  ushort4 ya = *reinterpret_cast<const ushort4*>(y + (size_t)s0 * TDIM + d);
  ushort4 yb = *reinterpret_cast<const ushort4*>(y + (size_t)s1 * TDIM + d);
  float4 o;
  o.x = w0 * bf2f(ya.x) + w1 * bf2f(yb.x);
  o.y = w0 * bf2f(ya.y) + w1 * bf2f(yb.y);
  o.z = w0 * bf2f(ya.z) + w1 * bf2f(yb.z);
  o.w = w0 * bf2f(ya.w) + w1 * bf2f(yb.w);
  *reinterpret_cast<float4*>(out + (size_t)t * TDIM + d) = o;
}

extern "C" void kernel_launch(void* const* d_in, const int* in_sizes, int n_in, void* d_out,
                              int out_size, void* d_ws, size_t ws_size, hipStream_t stream) {
  const float* x = (const float*)d_in[0];
  const float* Wr = (const float*)d_in[1];
  const float* W1 = (const float*)d_in[2];
  const float* b1 = (const float*)d_in[3];
  const float* W2 = (const float*)d_in[4];
  const float* b2 = (const float*)d_in[5];
  float* out = (float*)d_out;
  const int T = in_sizes[0] / TDIM;  // 8192

  size_t off = 0;
  auto alloc = [&](size_t bytes) {
    void* q = (char*)d_ws + off;
    off += (bytes + 255) & ~(size_t)255;
    return q;
  };
  bf16* xb = (bf16*)alloc((size_t)T * TDIM * 2);
  bf16* W1T = (bf16*)alloc((size_t)NEXP * TDIM * NHID * 2);
  bf16* W2T = (bf16*)alloc((size_t)NEXP * TDIM * NHID * 2);
  bf16* h = (bf16*)alloc((size_t)2 * T * NHID * 2);
  int* idx = (int*)alloc((size_t)T * 2 * 4);
  float* wtok = (float*)alloc((size_t)T * 2 * 4);
  int* perm = (int*)alloc((size_t)T * 2 * 4);
  int* islot = (int*)alloc((size_t)T * 2 * 4);
  int* cnt = (int*)alloc(256);  // cnt[8] | fill[8] | offs[8]
  int* fill = cnt + 8;
  int* offs = cnt + 16;
  // y (32 MB bf16) aliases W1T (64 MB): W1T dead after GEMM1; y written by GEMM2, read by combine.
  bf16* y = W1T;

  hipMemsetAsync(cnt, 0, 64, stream);  // cnt + fill

  cvt_x_kernel<<<(T * TDIM / 4 + 255) / 256, 256, 0, stream>>>(x, xb, T * TDIM / 4);
  transpose_cvt_kernel<<<dim3(NHID / 64, TDIM / 64, NEXP), 256, 0, stream>>>(W1, W1T, TDIM, NHID);
  transpose_cvt_kernel<<<dim3(TDIM / 64, NHID / 64, NEXP), 256, 0, stream>>>(W2, W2T, NHID, TDIM);
  router_kernel<<<T / 4, 256, 0, stream>>>(x, Wr, idx, wtok, cnt, T);
  scan_kernel<<<1, 64, 0, stream>>>(cnt, offs);
  build_perm_kernel<<<(T + 255) / 256, 256, 0, stream>>>(idx, offs, fill, perm, islot, T);

  // GEMM1: h[slot] = gelu(x[perm[slot]] @ W1[e] + b1[e]); worst case 8192 rows/expert
  moe_gemm8<TDIM, NHID, true, true><<<NEXP * 32 * 16, 512, 0, stream>>>(
      xb, W1T, b1, perm, cnt, offs, h, 32, 16);
  // GEMM2: y[slot] = h[slot] @ W2[e] + b2[e]
  moe_gemm8<NHID, TDIM, false, false><<<NEXP * 32 * 4, 512, 0, stream>>>(
      h, W2T, b2, perm, cnt, offs, y, 32, 4);

  combine_kernel<<<T, 256, 0, stream>>>(y, islot, wtok, out);
}

// Round 4
// 782.635 us; speedup vs baseline: 1.3850x; 1.0563x over previous
//
#include <hip/hip_runtime.h>
#include <hip/hip_bf16.h>

#define TDIM 1024
#define NEXP 8
#define NHID 4096

typedef __hip_bfloat16 bf16;
typedef __attribute__((ext_vector_type(8))) short bf16x8;
typedef __attribute__((ext_vector_type(8))) unsigned short u16x8;
typedef __attribute__((ext_vector_type(4))) float f32x4;

__device__ __forceinline__ void gload_lds16(void* lds, const void* g) {
  __builtin_amdgcn_global_load_lds(
      (const __attribute__((address_space(1))) unsigned int*)g,
      (__attribute__((address_space(3))) unsigned int*)lds, 16, 0, 0);
}

__device__ __forceinline__ unsigned short f2bf_bits(float f) {
  __hip_bfloat16 b = __float2bfloat16(f);
  unsigned short u;
  __builtin_memcpy(&u, &b, 2);
  return u;
}

__device__ __forceinline__ float bf2f(unsigned short u) {
  union { unsigned int i; float f; } c;
  c.i = ((unsigned int)u) << 16;
  return c.f;
}

// ---------------- prep: fused W1/W2 transpose+cvt, x cvt, router ----------------
__device__ __forceinline__ void do_transpose(const float* __restrict__ src, bf16* __restrict__ dst,
                                             int R, int C, int bx, int by, int tid,
                                             float (*tile)[65]) {
  const int c0 = bx * 64, r0 = by * 64;
#pragma unroll
  for (int i = 0; i < 4; ++i) {
    int s = tid + i * 256;
    int r = s >> 4, cg = (s & 15) * 4;
    float4 v = *reinterpret_cast<const float4*>(src + (size_t)(r0 + r) * C + c0 + cg);
    tile[r][cg] = v.x;
    tile[r][cg + 1] = v.y;
    tile[r][cg + 2] = v.z;
    tile[r][cg + 3] = v.w;
  }
  __syncthreads();
#pragma unroll
  for (int i = 0; i < 2; ++i) {
    int s = tid + i * 256;
    int c = s >> 3, rg = (s & 7) * 8;
    u16x8 o;
#pragma unroll
    for (int j = 0; j < 8; ++j) o[j] = f2bf_bits(tile[rg + j][c]);
    *reinterpret_cast<u16x8*>(dst + (size_t)(c0 + c) * R + r0 + rg) = o;
  }
}

// blocks [0,8192): W1 transpose; [8192,16384): W2 transpose; [16384,18432): router + x->bf16
__global__ __launch_bounds__(256) void prep_kernel(
    const float* __restrict__ W1, bf16* __restrict__ W1T, const float* __restrict__ W2,
    bf16* __restrict__ W2T, const float* __restrict__ x, bf16* __restrict__ xb,
    const float* __restrict__ Wr, int* __restrict__ idx, float* __restrict__ wtok,
    int* __restrict__ cnt, int T) {
  __shared__ float tile[64][65];
  const int pb = blockIdx.x;
  const int tid = threadIdx.x;
  if (pb < 8192) {
    // W1 [E][1024][4096] -> W1T [E][4096][1024]
    const int bx = pb & 63, by = (pb >> 6) & 15, e = pb >> 10;
    do_transpose(W1 + (size_t)e * TDIM * NHID, W1T + (size_t)e * TDIM * NHID, TDIM, NHID, bx, by,
                 tid, tile);
  } else if (pb < 16384) {
    // W2 [E][4096][1024] -> W2T [E][1024][4096]
    const int p = pb - 8192;
    const int bx = p & 15, by = (p >> 4) & 63, e = p >> 10;
    do_transpose(W2 + (size_t)e * TDIM * NHID, W2T + (size_t)e * TDIM * NHID, NHID, TDIM, bx, by,
                 tid, tile);
  } else {
    const int p = pb - 16384;
    const int wave = p * 4 + (tid >> 6);
    const int lane = tid & 63;
    if (wave >= T) return;
    const float4* xr4 = reinterpret_cast<const float4*>(x + (size_t)wave * TDIM);
    bf16* xbrow = xb + (size_t)wave * TDIM;
    float acc[NEXP];
#pragma unroll
    for (int e = 0; e < NEXP; ++e) acc[e] = 0.f;
    const float4* wr4 = reinterpret_cast<const float4*>(Wr);
#pragma unroll
    for (int i = 0; i < TDIM / 256; ++i) {
      float4 xv = xr4[lane + i * 64];
      // write bf16 copy
      ushort4 o;
      o.x = f2bf_bits(xv.x);
      o.y = f2bf_bits(xv.y);
      o.z = f2bf_bits(xv.z);
      o.w = f2bf_bits(xv.w);
      *reinterpret_cast<ushort4*>(xbrow + (lane + i * 64) * 4) = o;
      int row = (lane + i * 64) * 4;
#pragma unroll
      for (int j = 0; j < 4; ++j) {
        float xs = (&xv.x)[j];
        float4 wa = wr4[(row + j) * 2];
        float4 wb = wr4[(row + j) * 2 + 1];
        acc[0] += xs * wa.x;
        acc[1] += xs * wa.y;
        acc[2] += xs * wa.z;
        acc[3] += xs * wa.w;
        acc[4] += xs * wb.x;
        acc[5] += xs * wb.y;
        acc[6] += xs * wb.z;
        acc[7] += xs * wb.w;
      }
    }
#pragma unroll
    for (int e = 0; e < NEXP; ++e) {
      float v = acc[e];
#pragma unroll
      for (int s = 32; s; s >>= 1) v += __shfl_xor(v, s);
      acc[e] = v;
    }
    if (lane == 0) {
      int e0 = 0;
      float l0 = acc[0];
      for (int e = 1; e < NEXP; ++e)
        if (acc[e] > l0) { l0 = acc[e]; e0 = e; }
      int e1 = -1;
      float l1 = -INFINITY;
      for (int e = 0; e < NEXP; ++e)
        if (e != e0 && acc[e] > l1) { l1 = acc[e]; e1 = e; }
      float z = __expf(l1 - l0);
      idx[wave * 2] = e0;
      idx[wave * 2 + 1] = e1;
      wtok[wave * 2] = 1.f / (1.f + z);
      wtok[wave * 2 + 1] = z / (1.f + z);
      atomicAdd(&cnt[e0], 1);
      atomicAdd(&cnt[e1], 1);
    }
  }
}

__global__ void scan_kernel(const int* __restrict__ cnt, int* __restrict__ offs) {
  if (threadIdx.x == 0 && blockIdx.x == 0) {
    int s = 0;
    for (int e = 0; e < NEXP; ++e) { offs[e] = s; s += cnt[e]; }
  }
}

__global__ void build_perm_kernel(const int* __restrict__ idx, const int* __restrict__ offs,
                                  int* __restrict__ fill, int* __restrict__ perm,
                                  int* __restrict__ islot, int T) {
  int t = blockIdx.x * blockDim.x + threadIdx.x;
  if (t >= T) return;
#pragma unroll
  for (int k = 0; k < 2; ++k) {
    int e = idx[t * 2 + k];
    int p = offs[e] + atomicAdd(&fill[e], 1);
    perm[p] = t;
    islot[t * 2 + k] = p;
  }
}

// ---------------- grouped GEMM: 256x256x64, 8-phase, counted vmcnt, T2 swizzle ----------------
// 512 threads = 8 waves (2m x 4n). Quadrant order (0,0)->(1,0)->(1,1)->(0,1) so adjacent
// phases share one operand's register fragments: reads/tile = 12+8+4+8 = 32 ds_read_b128
// (vs 48 naive). Stage order per tile: A0,B0,A1,B1; vmcnt(6) at phases {0,1,2,4,5,6} retires
// exactly the half-tile each phase newly consumes (re-derived for this order; unchanged).
template <int KD, int ND, bool GATHER, bool GELU>
__global__ __launch_bounds__(512, 2) void moe_gemm8(
    const bf16* __restrict__ A, const bf16* __restrict__ BT, const float* __restrict__ bias,
    const int* __restrict__ perm, const int* __restrict__ cnt, const int* __restrict__ offs,
    bf16* __restrict__ Dst, int nm, int nn) {
  __shared__ short lds[65536];  // 128 KiB: buf*32768 + op*16384 + half*8192 (shorts)

  const int nwg = NEXP * nm * nn;
  const int bid = blockIdx.x;
  const int wg = (bid & 7) * (nwg >> 3) + (bid >> 3);  // bijective: nwg % 8 == 0
  const int e = wg / (nm * nn);
  const int rem = wg % (nm * nn);
  const int mb = rem / nn, nb = rem % nn;

  const int ce = cnt[e];
  const int m0 = mb * 256;
  if (m0 >= ce) return;
  const int base = offs[e];
  const int n0 = nb * 256;
  const int tid = threadIdx.x;
  const int lane = tid & 63;
  const int wid = tid >> 6;
  const int wm = wid >> 2, wn = wid & 3;
  const int lcol = lane & 15;
  const int lkg = (lane >> 4) * 8;

  // per-lane swizzled k offsets (shorts) for fragment reads
  const int kxs0 = ((lkg << 1) ^ ((lcol & 7) << 4)) >> 1;
  const int kxs1 = (((lkg + 32) << 1) ^ ((lcol & 7) << 4)) >> 1;
  int aRow[4], bRow[2];
#pragma unroll
  for (int mm = 0; mm < 4; ++mm) aRow[mm] = (wm * 64 + mm * 16 + lcol) << 6;
#pragma unroll
  for (int n2 = 0; n2 < 2; ++n2) bRow[n2] = (wn * 32 + n2 * 16 + lcol) << 6;

  // staging pointers: slot s = tid + i*512 -> row s>>3 (0..127), kslot s&7;
  // source k pre-swizzled: kslot_src = kslot ^ (row&7)
  const bf16* aP[2][2];
  const bf16* bP[2][2];
#pragma unroll
  for (int h = 0; h < 2; ++h)
#pragma unroll
    for (int i = 0; i < 2; ++i) {
      int s = tid + i * 512;
      int srow = s >> 3;
      int kof = ((s & 7) ^ (srow & 7)) * 8;
      int grow = m0 + h * 128 + srow;
      if (grow > ce - 1) grow = ce - 1;
      size_t arow = GATHER ? (size_t)perm[base + grow] : (size_t)(base + grow);
      aP[h][i] = A + arow * KD + kof;
      bP[h][i] = BT + ((size_t)e * ND + n0 + h * 128 + srow) * KD + kof;
    }

  f32x4 acc[8][4];
#pragma unroll
  for (int m = 0; m < 8; ++m)
#pragma unroll
    for (int n = 0; n < 4; ++n) acc[m][n] = (f32x4){0.f, 0.f, 0.f, 0.f};

  bf16x8 fA[4][2], fB[2][2];  // persist across phases (all indexing compile-time)

#define STAGE(SBUF, OP, HF, kof)                                                     \
  {                                                                                  \
    char* sd = (char*)lds + (SBUF) * 65536 + (OP) * 32768 + (HF) * 16384 + tid * 16; \
    gload_lds16(sd, ((OP) ? bP[HF][0] : aP[HF][0]) + (kof));                         \
    gload_lds16(sd + 8192, ((OP) ? bP[HF][1] : aP[HF][1]) + (kof));                  \
  }

// QM,QN: quadrant; RA/RB: read fresh A/B fragments (else reuse registers);
// SOP,SHF: staged (op,half); SBUF: stage buffer; CBUF: consume buffer.
#define PHASE(QM, QN, RA, RB, SOP, SHF, SBUF, CBUF, kof, DO_VM)                      \
  {                                                                                  \
    STAGE(SBUF, SOP, SHF, kof);                                                      \
    if (DO_VM) asm volatile("s_waitcnt vmcnt(6)" ::: "memory");                      \
    __builtin_amdgcn_s_barrier();                                                    \
    asm volatile("" ::: "memory");                                                   \
    if (RA) {                                                                        \
      const short* Ab = lds + (CBUF) * 32768 + (QM) * 8192;                          \
      _Pragma("unroll") for (int mm = 0; mm < 4; ++mm) {                             \
        fA[mm][0] = *(const bf16x8*)(Ab + aRow[mm] + kxs0);                          \
        fA[mm][1] = *(const bf16x8*)(Ab + aRow[mm] + kxs1);                          \
      }                                                                              \
    }                                                                                \
    if (RB) {                                                                        \
      const short* Bb = lds + (CBUF) * 32768 + 16384 + (QN) * 8192;                  \
      _Pragma("unroll") for (int n2 = 0; n2 < 2; ++n2) {                             \
        fB[n2][0] = *(const bf16x8*)(Bb + bRow[n2] + kxs0);                          \
        fB[n2][1] = *(const bf16x8*)(Bb + bRow[n2] + kxs1);                          \
      }                                                                              \
    }                                                                                \
    asm volatile("s_waitcnt lgkmcnt(0)" ::: "memory");                               \
    __builtin_amdgcn_s_setprio(1);                                                   \
    _Pragma("unroll") for (int mm = 0; mm < 4; ++mm)                                 \
        _Pragma("unroll") for (int n2 = 0; n2 < 2; ++n2) {                           \
      acc[(QM) * 4 + mm][(QN) * 2 + n2] = __builtin_amdgcn_mfma_f32_16x16x32_bf16(   \
          fA[mm][0], fB[n2][0], acc[(QM) * 4 + mm][(QN) * 2 + n2], 0, 0, 0);         \
      acc[(QM) * 4 + mm][(QN) * 2 + n2] = __builtin_amdgcn_mfma_f32_16x16x32_bf16(   \
          fA[mm][1], fB[n2][1], acc[(QM) * 4 + mm][(QN) * 2 + n2], 0, 0, 0);         \
    }                                                                                \
    __builtin_amdgcn_s_setprio(0);                                                   \
  }

  // prologue: tile 0 -> buf0, in need-order A0,B0,A1,B1
  STAGE(0, 0, 0, 0);
  STAGE(0, 1, 0, 0);
  STAGE(0, 0, 1, 0);
  STAGE(0, 1, 1, 0);

  const int NI = KD / 128;
  for (int itv = 0; itv < NI; ++itv) {
    const int k1 = itv * 128 + 64;  // tile 2it+1 -> buf1 (consumed ph4-7)
    int k2 = itv * 128 + 128;       // tile 2it+2 -> buf0 (consumed next iter)
    if (k2 >= KD) k2 = 0;           // last iter: dummy restage (never consumed, keeps vmcnt math)
    PHASE(0, 0, 1, 1, 0, 0, 1, 0, k1, 1)
    PHASE(1, 0, 1, 0, 1, 0, 1, 0, k1, 1)
    PHASE(1, 1, 0, 1, 0, 1, 1, 0, k1, 1)
    PHASE(0, 1, 1, 0, 1, 1, 1, 0, k1, 0)
    PHASE(0, 0, 1, 1, 0, 0, 0, 1, k2, 1)
    PHASE(1, 0, 1, 0, 1, 0, 0, 1, k2, 1)
    PHASE(1, 1, 0, 1, 0, 1, 0, 1, k2, 1)
    PHASE(0, 1, 1, 0, 1, 1, 0, 1, k2, 0)
  }
#undef PHASE
#undef STAGE

  // epilogue: row = m0 + QM*128 + wm*64 + mm*16 + (lane>>4)*4 + r ;
  //           col = n0 + QN*128 + wn*32 + n2*16 + lcol
  float bv[4];
#pragma unroll
  for (int ni = 0; ni < 4; ++ni)
    bv[ni] = bias[e * ND + n0 + (ni >> 1) * 128 + wn * 32 + (ni & 1) * 16 + lcol];
  const int lr4 = (lane >> 4) * 4;
#pragma unroll
  for (int mi = 0; mi < 8; ++mi) {
    const int rbase = m0 + (mi >> 2) * 128 + wm * 64 + (mi & 3) * 16 + lr4;
#pragma unroll
    for (int r = 0; r < 4; ++r) {
      int grow = rbase + r;
      if (grow < ce) {
        bf16* drow = Dst + (size_t)(base + grow) * ND;
#pragma unroll
        for (int ni = 0; ni < 4; ++ni) {
          int col = n0 + (ni >> 1) * 128 + wn * 32 + (ni & 1) * 16 + lcol;
          float v = acc[mi][ni][r] + bv[ni];
          if (GELU) v = 0.5f * v * (1.0f + erff(v * 0.70710678118654752f));
          drow[col] = __float2bfloat16(v);
        }
      }
    }
  }
}

// ---------------- combine: out[t] = w0*y[slot0] + w1*y[slot1] ----------------
__global__ void combine_kernel(const bf16* __restrict__ y, const int* __restrict__ islot,
                               const float* __restrict__ wtok, float* __restrict__ out) {
  const int t = blockIdx.x;
  const int d = threadIdx.x * 4;
  const int s0 = islot[t * 2], s1 = islot[t * 2 + 1];
  const float w0 = wtok[t * 2], w1 = wtok[t * 2 + 1];
  ushort4 ya = *reinterpret_cast<const ushort4*>(y + (size_t)s0 * TDIM + d);
  ushort4 yb = *reinterpret_cast<const ushort4*>(y + (size_t)s1 * TDIM + d);
  float4 o;
  o.x = w0 * bf2f(ya.x) + w1 * bf2f(yb.x);
  o.y = w0 * bf2f(ya.y) + w1 * bf2f(yb.y);
  o.z = w0 * bf2f(ya.z) + w1 * bf2f(yb.z);
  o.w = w0 * bf2f(ya.w) + w1 * bf2f(yb.w);
  *reinterpret_cast<float4*>(out + (size_t)t * TDIM + d) = o;
}

extern "C" void kernel_launch(void* const* d_in, const int* in_sizes, int n_in, void* d_out,
                              int out_size, void* d_ws, size_t ws_size, hipStream_t stream) {
  const float* x = (const float*)d_in[0];
  const float* Wr = (const float*)d_in[1];
  const float* W1 = (const float*)d_in[2];
  const float* b1 = (const float*)d_in[3];
  const float* W2 = (const float*)d_in[4];
  const float* b2 = (const float*)d_in[5];
  float* out = (float*)d_out;
  const int T = in_sizes[0] / TDIM;  // 8192

  size_t off = 0;
  auto alloc = [&](size_t bytes) {
    void* q = (char*)d_ws + off;
    off += (bytes + 255) & ~(size_t)255;
    return q;
  };
  bf16* xb = (bf16*)alloc((size_t)T * TDIM * 2);
  bf16* W1T = (bf16*)alloc((size_t)NEXP * TDIM * NHID * 2);
  bf16* W2T = (bf16*)alloc((size_t)NEXP * TDIM * NHID * 2);
  bf16* h = (bf16*)alloc((size_t)2 * T * NHID * 2);
  int* idx = (int*)alloc((size_t)T * 2 * 4);
  float* wtok = (float*)alloc((size_t)T * 2 * 4);
  int* perm = (int*)alloc((size_t)T * 2 * 4);
  int* islot = (int*)alloc((size_t)T * 2 * 4);
  int* cnt = (int*)alloc(256);  // cnt[8] | fill[8] | offs[8]
  int* fill = cnt + 8;
  int* offs = cnt + 16;
  // y (32 MB bf16) aliases W1T (64 MB): W1T dead after GEMM1; y written by GEMM2, read by combine.
  bf16* y = W1T;

  hipMemsetAsync(cnt, 0, 64, stream);  // cnt + fill

  prep_kernel<<<18432, 256, 0, stream>>>(W1, W1T, W2, W2T, x, xb, Wr, idx, wtok, cnt, T);
  scan_kernel<<<1, 64, 0, stream>>>(cnt, offs);
  build_perm_kernel<<<(T + 255) / 256, 256, 0, stream>>>(idx, offs, fill, perm, islot, T);

  // GEMM1: h[slot] = gelu(x[perm[slot]] @ W1[e] + b1[e]); worst case 8192 rows/expert
  moe_gemm8<TDIM, NHID, true, true><<<NEXP * 32 * 16, 512, 0, stream>>>(
      xb, W1T, b1, perm, cnt, offs, h, 32, 16);
  // GEMM2: y[slot] = h[slot] @ W2[e] + b2[e]
  moe_gemm8<NHID, TDIM, false, false><<<NEXP * 32 * 4, 512, 0, stream>>>(
      h, W2T, b2, perm, cnt, offs, y, 32, 4);

  combine_kernel<<<T, 256, 0, stream>>>(y, islot, wtok, out);
}